// Round 15
// baseline (421.666 us; speedup 1.0000x reference)
//
#include <hip/hip_runtime.h>
#include <math.h>

// Workspace layout (floats):
//   [0,256)        T     : full symmetric Re(U^H M U)
//   [256,800)      S     : atomic-fallback accumulators S[b][q]
//   [800,832)      n     : atomic-fallback squared norms
//   [1024,5376)    Spart : partials [b][q][oct]  32*17*8
//   [5376,5632)    npart : norm partials [b][oct] 32*8
#define WS_TU    0
#define WS_S     256
#define WS_N     800
#define WS_PART  1024
#define WS_NPART 5376
#define WS_NEED_BYTES (5632 * 4)

typedef _Float16 half8 __attribute__((ext_vector_type(8)));
typedef _Float16 half4_t __attribute__((ext_vector_type(4)));
typedef float f32x4 __attribute__((ext_vector_type(4)));

__device__ inline float2 cmul2(float2 a, float2 b) {
  return make_float2(a.x * b.x - a.y * b.y, a.x * b.y + a.y * b.x);
}

__device__ inline int ringperm(int x) {
  if ((x >> 3) & 1) x ^= 4;
  if ((x >> 2) & 1) x ^= 2;
  if ((x >> 1) & 1) x ^= 1;
  if (x & 1)        x ^= 8;
  return x;
}

__device__ inline float2 yzy_elem(const float* wgt, int layer, int r, int c) {
  float2 prod = make_float2(1.f, 0.f);
#pragma unroll
  for (int k = 0; k < 4; k++) {
    float t0 = wgt[layer * 12 + 3 * k + 0];
    float t1 = wgt[layer * 12 + 3 * k + 1];
    float t2 = wgt[layer * 12 + 3 * k + 2];
    float s0, c0, s1, c1, s2, c2;
    sincosf(0.5f * t0, &s0, &c0);
    sincosf(0.5f * t1, &s1, &c1);
    sincosf(0.5f * t2, &s2, &c2);
    float A = c2 * c0, B = s2 * s0, C = c2 * s0, D = s2 * c0;
    float2 m00 = make_float2( c1 * (A - B), -s1 * (A + B));
    float2 m01 = make_float2(-c1 * (C + D),  s1 * (C - D));
    float2 m10 = make_float2( c1 * (C + D),  s1 * (C - D));
    float2 m11 = make_float2( c1 * (A - B),  s1 * (A + B));
    int rb = (r >> (3 - k)) & 1, cb = (c >> (3 - k)) & 1;
    float2 mm = rb ? (cb ? m11 : m10) : (cb ? m01 : m00);
    prod = cmul2(prod, mm);
  }
  return prod;
}

__global__ void build_T_kernel(const float* __restrict__ wgt, float* __restrict__ ws) {
  __shared__ float2 U[256], Y[256], W[256];
  const int t = threadIdx.x;
  const int r = t >> 4, c = t & 15;

  for (int k = t; k < 576; k += 256) ws[WS_S + k] = 0.f;

  U[t] = yzy_elem(wgt, 0, r, c);
  __syncthreads();
  W[ringperm(r) * 16 + c] = U[t];
  __syncthreads(); U[t] = W[t]; __syncthreads();
  Y[t] = yzy_elem(wgt, 1, r, c);
  __syncthreads();
  {
    float2 s = make_float2(0.f, 0.f);
#pragma unroll
    for (int k = 0; k < 16; k++) {
      float2 pr = cmul2(Y[r * 16 + k], U[k * 16 + c]);
      s.x += pr.x; s.y += pr.y;
    }
    W[t] = s;
  }
  __syncthreads(); U[t] = W[t]; __syncthreads();
  W[ringperm(r) * 16 + c] = U[t];
  __syncthreads(); U[t] = W[t]; __syncthreads();
  Y[t] = yzy_elem(wgt, 2, r, c);
  __syncthreads();
  {
    float2 s = make_float2(0.f, 0.f);
#pragma unroll
    for (int k = 0; k < 16; k++) {
      float2 pr = cmul2(Y[r * 16 + k], U[k * 16 + c]);
      s.x += pr.x; s.y += pr.y;
    }
    W[t] = s;
  }
  __syncthreads(); U[t] = W[t]; __syncthreads();
  Y[t] = U[(r ^ 15) * 16 + c];
  __syncthreads();
  float s_re = 0.f;
#pragma unroll
  for (int k = 0; k < 16; k++) {
    float2 u = U[k * 16 + r], m = Y[k * 16 + c];
    s_re += u.x * m.x + u.y * m.y;
  }
  ws[WS_TU + t] = s_re;
}

// XOR-fold swizzle on 16B-block index
__device__ inline int swzB(int B) {
  int h = B >> 3;
  int f = (h ^ (h >> 3) ^ (h >> 6)) & 7;
  return B ^ f;
}

// 512-thread Gram window: 8 waves x 4 independent depth-1 MFMA chains.
template <int P>
__device__ __forceinline__ float windowM(const half8* __restrict__ HB,
                                         const float* __restrict__ Tr, int t) {
  const int w = t >> 6, l = t & 63, g = (l >> 4) & 3, i = l & 15;
  f32x4 hh[4] = {{0.f, 0.f, 0.f, 0.f}, {0.f, 0.f, 0.f, 0.f},
                 {0.f, 0.f, 0.f, 0.f}, {0.f, 0.f, 0.f, 0.f}};
#pragma unroll
  for (int c = 0; c < 4; c++) {
    int rest = (w << 4) | (c << 2) | g;  // 7-bit slab id
    int rl = rest & ((1 << (P - 3)) - 1), rh = rest >> (P - 3);
    int pos = (rl << 3) | (i << P) | (rh << (P + 4));
    half8 fr = HB[swzB(pos >> 3)];
    hh[c] = __builtin_amdgcn_mfma_f32_16x16x32_f16(fr, fr, hh[c], 0, 0, 0);
  }
  float part = 0.f;
#pragma unroll
  for (int reg = 0; reg < 4; reg++)
    part = fmaf(Tr[reg], (hh[0][reg] + hh[1][reg]) + (hh[2][reg] + hh[3][reg]), part);
  return part;
}

__device__ __forceinline__ void issue_loads0(float4* pf, const float4* __restrict__ s4, int t) {
#pragma unroll
  for (int j = 0; j < 4; j++) {
    int B = j * 512 + t;
    pf[2 * j]     = s4[2 * B];
    pf[2 * j + 1] = s4[2 * B + 1];
  }
}
__device__ __forceinline__ void issue_loads2(float4* pf, const float4* __restrict__ s4, int t) {
#pragma unroll
  for (int j = 0; j < 4; j++) {
    int B = j * 512 + t;
    int row = B >> 2, c4 = (B & 3) * 2;
    pf[2 * j]     = s4[row * 512 + c4];
    pf[2 * j + 1] = s4[row * 512 + c4 + 1];
  }
}

__device__ __forceinline__ void convert_write(half8* __restrict__ buf, const float4* pf,
                                              half8* h, int t) {
#pragma unroll
  for (int j = 0; j < 4; j++) {
    float4 aa = pf[2 * j], cc = pf[2 * j + 1];
    half8 hh;
    hh[0] = (_Float16)aa.x; hh[1] = (_Float16)aa.y; hh[2] = (_Float16)aa.z; hh[3] = (_Float16)aa.w;
    hh[4] = (_Float16)cc.x; hh[5] = (_Float16)cc.y; hh[6] = (_Float16)cc.z; hh[7] = (_Float16)cc.w;
    h[j] = hh;
    buf[swzB(j * 512 + t)] = hh;
  }
}

// register-resident P=3 window + squared-norm from the Gram trace
__device__ __forceinline__ void p3_trace(const half8* h, const float* Treg, int g, int i,
                                         float& p0, float& ns) {
  f32x4 a[4] = {{0.f, 0.f, 0.f, 0.f}, {0.f, 0.f, 0.f, 0.f},
                {0.f, 0.f, 0.f, 0.f}, {0.f, 0.f, 0.f, 0.f}};
#pragma unroll
  for (int j = 0; j < 4; j++)
    a[j] = __builtin_amdgcn_mfma_f32_16x16x32_f16(h[j], h[j], a[j], 0, 0, 0);
#pragma unroll
  for (int reg = 0; reg < 4; reg++) {
    float hm = (a[0][reg] + a[1][reg]) + (a[2][reg] + a[3][reg]);
    p0 = fmaf(Treg[reg], hm, p0);
    if (g == (i >> 2) && reg == (i & 3)) ns += hm;
  }
}

// 512 blocks x 512 threads; 2 blocks/CU (64 KB LDS), double-buffered tiles.
// Each block: 8 chunks, loads for chunk c+1 in flight under windows of chunk c.
// mode = bid&1: 0 = contiguous chunks (reg-P3+trace, LDS p=4..10, reg-transpose
// image1 p=0..2); 2 = strided tiles (p=11..16).
__global__ __launch_bounds__(512, 4) void passAll_kernel(const float* __restrict__ vb,
                                                         float* ws, int use_part) {
  __shared__ half8 HB[2][2048];   // 2 x 32 KB; reduce scratch aliases HB[0]
  const int t = threadIdx.x;
  const int bid = blockIdx.x;

  const int mode = (bid & 1) ? 2 : 0;
  const int sub = bid >> 1;            // [0,256)
  const int b = sub >> 3, oct = sub & 7;
  const int chunk0 = oct * 8;
  const int l = t & 63, g = (l >> 4) & 3, i = l & 15;

  float Treg[4];
#pragma unroll
  for (int reg = 0; reg < 4; reg++) Treg[reg] = ws[WS_TU + ((g * 4 + reg) << 4) + i];

  float part[11];
#pragma unroll
  for (int k = 0; k < 11; k++) part[k] = 0.f;
  float nsum = 0.f;

  float4 pf[8];
  half8 h[4];
  const float4* vb4 = (const float4*)vb;

  if (mode == 0) {
    const float4* srcb = vb4 + ((size_t)b << 18);
    issue_loads0(pf, srcb + ((size_t)chunk0 << 12), t);
    convert_write(HB[0], pf, h, t);
    p3_trace(h, Treg, g, i, part[0], nsum);
    __syncthreads();
    issue_loads0(pf, srcb + ((size_t)(chunk0 + 1) << 12), t);
#pragma unroll
    for (int c = 0; c < 8; c++) {
      half8* buf = HB[c & 1];
      // image0 LDS windows p=4..10 (q 12..6); chunk c+1 loads in flight
      part[1] += windowM<4>(buf, Treg, t);
      part[2] += windowM<5>(buf, Treg, t);
      part[3] += windowM<6>(buf, Treg, t);
      part[4] += windowM<7>(buf, Treg, t);
      part[5] += windowM<8>(buf, Treg, t);
      part[6] += windowM<9>(buf, Treg, t);
      part[7] += windowM<10>(buf, Treg, t);
      __syncthreads();  // image0 reads done before overwrite
      // image1 (rot+3) from live registers: x[4096j+8t+e]; t<256 -> u even,
      // t>=256 -> u odd of block c=8*(t&255)+e (k-scrambled, Gram-invariant)
      {
        const int tt = t & 255, hf8 = t >> 8;
#pragma unroll
        for (int e = 0; e < 8; e++) {
          half4_t v = {h[0][e], h[1][e], h[2][e], h[3][e]};
          *(half4_t*)((char*)buf + swzB(8 * tt + e) * 16 + hf8 * 8) = v;
        }
      }
      __syncthreads();
      part[8]  += windowM<3>(buf, Treg, t);  // q16
      part[9]  += windowM<4>(buf, Treg, t);  // q15
      part[10] += windowM<5>(buf, Treg, t);  // q14
      if (c < 7) {
        convert_write(HB[(c + 1) & 1], pf, h, t);
        p3_trace(h, Treg, g, i, part[0], nsum);
        __syncthreads();
        if (c < 6) issue_loads0(pf, srcb + ((size_t)(chunk0 + c + 2) << 12), t);
      }
    }
  } else {
    const float4* srcb = vb4 + ((size_t)b << 18);
    issue_loads2(pf, srcb + chunk0 * 8, t);
    convert_write(HB[0], pf, h, t);
    __syncthreads();
    issue_loads2(pf, srcb + (chunk0 + 1) * 8, t);
#pragma unroll
    for (int c = 0; c < 8; c++) {
      half8* buf = HB[c & 1];
      part[0] += windowM<5>(buf, Treg, t);
      part[1] += windowM<6>(buf, Treg, t);
      part[2] += windowM<7>(buf, Treg, t);
      part[3] += windowM<8>(buf, Treg, t);
      part[4] += windowM<9>(buf, Treg, t);
      part[5] += windowM<10>(buf, Treg, t);
      if (c < 7) {
        convert_write(HB[(c + 1) & 1], pf, h, t);
        __syncthreads();
        if (c < 6) issue_loads2(pf, srcb + (chunk0 + c + 2) * 8, t);
      }
    }
  }

  // reduce: alias scratch into HB[0] (last reads of HB[0] fenced by iter-6
  // barrier; iter-7 windows read HB[1] only)
  float* red2 = (float*)HB;  // 12*512 floats = 24 KB
#pragma unroll
  for (int k = 0; k < 11; k++) red2[k * 512 + t] = part[k];
  red2[11 * 512 + t] = nsum;
  __syncthreads();

  const int win = t >> 5, idx32 = t & 31;
  const float4* r4 = (const float4*)red2;
  float s1 = 0.f;
#pragma unroll
  for (int m = 0; m < 4; m++) {
    float4 q = r4[win * 128 + m * 32 + idx32];
    s1 += (q.x + q.y) + (q.z + q.w);
  }
#pragma unroll
  for (int off = 16; off; off >>= 1) s1 += __shfl_down(s1, off, 32);

  if (idx32 == 0) {
    if (mode == 0) {
      if (win < 11) {
        int q = (win < 8) ? (13 - win) : (24 - win);
        if (use_part) ws[WS_PART + (b * 17 + q) * 8 + oct] = s1;
        else          atomicAdd(ws + WS_S + b * 17 + q, s1);
      } else if (win == 11) {
        if (use_part) ws[WS_NPART + b * 8 + oct] = s1;
        else          atomicAdd(ws + WS_N + b, s1);
      }
    } else {
      if (win < 6) {
        int q = 5 - win;
        if (use_part) ws[WS_PART + (b * 17 + q) * 8 + oct] = s1;
        else          atomicAdd(ws + WS_S + b * 17 + q, s1);
      }
    }
  }
}

__global__ void finalize_kernel(const float* __restrict__ ws, float* __restrict__ out,
                                int use_part) {
  int i = blockIdx.x * 256 + threadIdx.x;
  if (i < 544) {
    int b = i / 17;
    float s, n;
    if (use_part) {
      const float* sp = ws + WS_PART + i * 8;
      s = 0.f;
#pragma unroll
      for (int c = 0; c < 8; c++) s += sp[c];
      const float* np = ws + WS_NPART + b * 8;
      n = 0.f;
#pragma unroll
      for (int c = 0; c < 8; c++) n += np[c];
    } else {
      s = ws[WS_S + i];
      n = ws[WS_N + b];
    }
    out[i] = s / fmaxf(n, 1e-24f);
  }
}

extern "C" void kernel_launch(void* const* d_in, const int* in_sizes, int n_in,
                              void* d_out, int out_size, void* d_ws, size_t ws_size,
                              hipStream_t stream) {
  const float* vb  = (const float*)d_in[0];
  const float* wgt = (const float*)d_in[1];
  float* out = (float*)d_out;
  float* ws  = (float*)d_ws;
  int use_part = (ws_size >= (size_t)WS_NEED_BYTES) ? 1 : 0;

  build_T_kernel<<<1, 256, 0, stream>>>(wgt, ws);
  passAll_kernel<<<512, 512, 0, stream>>>(vb, ws, use_part);
  finalize_kernel<<<3, 256, 0, stream>>>(ws, out, use_part);
}

// Round 16
// 58.740 us; speedup vs baseline: 7.1785x; 7.1785x over previous
//
#include <hip/hip_runtime.h>
#include <math.h>

// Workspace layout (floats):
//   [0,256)          T     : full symmetric Re(U^H M U)
//   [256,800)        S     : atomic-fallback accumulators S[b][q]
//   [800,832)        n     : atomic-fallback squared norms
//   [1024,35840)     Spart : partials [b][q][chunk]  32*17*64
//   [35840,37888)    npart : norm partials [b][chunk] 32*64
#define WS_TU    0
#define WS_S     256
#define WS_N     800
#define WS_PART  1024
#define WS_NPART 35840
#define WS_NEED_BYTES ((WS_NPART + 2048) * 4)

typedef _Float16 half8 __attribute__((ext_vector_type(8)));
typedef float f32x4 __attribute__((ext_vector_type(4)));

__device__ inline float2 cmul2(float2 a, float2 b) {
  return make_float2(a.x * b.x - a.y * b.y, a.x * b.y + a.y * b.x);
}

__device__ inline int ringperm(int x) {
  if ((x >> 3) & 1) x ^= 4;
  if ((x >> 2) & 1) x ^= 2;
  if ((x >> 1) & 1) x ^= 1;
  if (x & 1)        x ^= 8;
  return x;
}

__device__ inline float2 yzy_elem(const float* wgt, int layer, int r, int c) {
  float2 prod = make_float2(1.f, 0.f);
#pragma unroll
  for (int k = 0; k < 4; k++) {
    float t0 = wgt[layer * 12 + 3 * k + 0];
    float t1 = wgt[layer * 12 + 3 * k + 1];
    float t2 = wgt[layer * 12 + 3 * k + 2];
    float s0, c0, s1, c1, s2, c2;
    sincosf(0.5f * t0, &s0, &c0);
    sincosf(0.5f * t1, &s1, &c1);
    sincosf(0.5f * t2, &s2, &c2);
    float A = c2 * c0, B = s2 * s0, C = c2 * s0, D = s2 * c0;
    float2 m00 = make_float2( c1 * (A - B), -s1 * (A + B));
    float2 m01 = make_float2(-c1 * (C + D),  s1 * (C - D));
    float2 m10 = make_float2( c1 * (C + D),  s1 * (C - D));
    float2 m11 = make_float2( c1 * (A - B),  s1 * (A + B));
    int rb = (r >> (3 - k)) & 1, cb = (c >> (3 - k)) & 1;
    float2 mm = rb ? (cb ? m11 : m10) : (cb ? m01 : m00);
    prod = cmul2(prod, mm);
  }
  return prod;
}

__global__ void build_T_kernel(const float* __restrict__ wgt, float* __restrict__ ws) {
  __shared__ float2 U[256], Y[256], W[256];
  const int t = threadIdx.x;
  const int r = t >> 4, c = t & 15;

  // zero the atomic-fallback accumulators (no separate memset dispatch)
  for (int k = t; k < 576; k += 256) ws[WS_S + k] = 0.f;

  U[t] = yzy_elem(wgt, 0, r, c);
  __syncthreads();
  W[ringperm(r) * 16 + c] = U[t];
  __syncthreads(); U[t] = W[t]; __syncthreads();
  Y[t] = yzy_elem(wgt, 1, r, c);
  __syncthreads();
  {
    float2 s = make_float2(0.f, 0.f);
#pragma unroll
    for (int k = 0; k < 16; k++) {
      float2 pr = cmul2(Y[r * 16 + k], U[k * 16 + c]);
      s.x += pr.x; s.y += pr.y;
    }
    W[t] = s;
  }
  __syncthreads(); U[t] = W[t]; __syncthreads();
  W[ringperm(r) * 16 + c] = U[t];
  __syncthreads(); U[t] = W[t]; __syncthreads();
  Y[t] = yzy_elem(wgt, 2, r, c);
  __syncthreads();
  {
    float2 s = make_float2(0.f, 0.f);
#pragma unroll
    for (int k = 0; k < 16; k++) {
      float2 pr = cmul2(Y[r * 16 + k], U[k * 16 + c]);
      s.x += pr.x; s.y += pr.y;
    }
    W[t] = s;
  }
  __syncthreads(); U[t] = W[t]; __syncthreads();
  Y[t] = U[(r ^ 15) * 16 + c];
  __syncthreads();
  float s_re = 0.f;
#pragma unroll
  for (int k = 0; k < 16; k++) {
    float2 u = U[k * 16 + r], m = Y[k * 16 + c];
    s_re += u.x * m.x + u.y * m.y;
  }
  ws[WS_TU + t] = s_re;  // full symmetric T
}

// XOR-fold swizzle on 16B-block index
__device__ inline int swzB(int B) {
  int h = B >> 3;
  int f = (h ^ (h >> 3) ^ (h >> 6)) & 7;
  return B ^ f;
}

// Gram-window via MFMA, FOUR accumulator chains of depth 2.
// LDS: 2048 16B blocks of 8 f16, block index swizzled. i-field at pos bits [P,P+4).
template <int P>
__device__ inline float windowM(const half8* __restrict__ HB, const float* __restrict__ Tr) {
  const int t = threadIdx.x;
  const int w = t >> 6, l = t & 63, g = l >> 4, i = l & 15;
  f32x4 hh[4] = {{0.f, 0.f, 0.f, 0.f}, {0.f, 0.f, 0.f, 0.f},
                 {0.f, 0.f, 0.f, 0.f}, {0.f, 0.f, 0.f, 0.f}};
#pragma unroll
  for (int s = 0; s < 2; s++) {
#pragma unroll
    for (int c = 0; c < 4; c++) {
      int rest = (w << 5) | ((s * 4 + c) << 2) | g;  // 7-bit rest
      int rl = rest & ((1 << (P - 3)) - 1), rh = rest >> (P - 3);
      int pos = (rl << 3) | (i << P) | (rh << (P + 4));
      half8 fr = HB[swzB(pos >> 3)];
      hh[c] = __builtin_amdgcn_mfma_f32_16x16x32_f16(fr, fr, hh[c], 0, 0, 0);
    }
  }
  float part = 0.f;
#pragma unroll
  for (int reg = 0; reg < 4; reg++)
    part = fmaf(Tr[reg], (hh[0][reg] + hh[1][reg]) + (hh[2][reg] + hh[3][reg]), part);
  return part;
}

// modes: 0 = contiguous chunk: window P=3 REGISTER-RESIDENT (staging fragments
//            are valid P=3 MFMA fragments: i = pos[3,7) = lane&15; rest =
//            g|w<<2|j<<4 covers [0,128) over 4 waves x 8 j), then LDS windows
//            p=4..10, then LDS re-read + in-place transpose -> image1 (rot+3,
//            p=0..2); norms. ONE global read.
//        2 = strided row tile (p=11..16), grid tail (L3-warm).
__global__ __launch_bounds__(256, 4) void passAll_kernel(const float* __restrict__ vb,
                                                         float* ws, int use_part) {
  __shared__ half8 HB[2048];   // exactly 32 KB; reduce scratch aliases it later
  const int t = threadIdx.x;
  const int bid = blockIdx.x;

  const int mode = (bid < 2048) ? 0 : 2;
  const int idx = (bid < 2048) ? bid : bid - 2048;
  const int b = idx >> 6, chunk = idx & 63;
  const int l = t & 63, g = (l >> 4) & 3, i = l & 15;

  // per-thread T values: T[g*4+reg][i] is all this lane ever needs
  float Treg[4];
#pragma unroll
  for (int reg = 0; reg < 4; reg++) Treg[reg] = ws[WS_TU + ((g * 4 + reg) << 4) + i];

  float part[11];
#pragma unroll
  for (int k = 0; k < 11; k++) part[k] = 0.f;

  float nsum = 0.f;
  if (mode == 0) {
    const float4* src4 = ((const float4*)vb) + ((size_t)b << 18) + ((size_t)chunk << 12);
    half8 h[8];  // staged fragments, consumed by register-resident P=3 below
#pragma unroll
    for (int j = 0; j < 8; j++) {
      int B = j * 256 + t;
      float4 aa = src4[2 * B], cc = src4[2 * B + 1];
      nsum = fmaf(aa.x, aa.x, nsum); nsum = fmaf(aa.y, aa.y, nsum);
      nsum = fmaf(aa.z, aa.z, nsum); nsum = fmaf(aa.w, aa.w, nsum);
      nsum = fmaf(cc.x, cc.x, nsum); nsum = fmaf(cc.y, cc.y, nsum);
      nsum = fmaf(cc.z, cc.z, nsum); nsum = fmaf(cc.w, cc.w, nsum);
      half8 hh;
      hh[0] = (_Float16)aa.x; hh[1] = (_Float16)aa.y; hh[2] = (_Float16)aa.z; hh[3] = (_Float16)aa.w;
      hh[4] = (_Float16)cc.x; hh[5] = (_Float16)cc.y; hh[6] = (_Float16)cc.z; hh[7] = (_Float16)cc.w;
      h[j] = hh;
      HB[swzB(B)] = hh;
    }
    // window P=3 (q=13) straight from registers; runs under the barrier wait
    {
      f32x4 hh[4] = {{0.f, 0.f, 0.f, 0.f}, {0.f, 0.f, 0.f, 0.f},
                     {0.f, 0.f, 0.f, 0.f}, {0.f, 0.f, 0.f, 0.f}};
#pragma unroll
      for (int j = 0; j < 8; j++)
        hh[j & 3] = __builtin_amdgcn_mfma_f32_16x16x32_f16(h[j], h[j], hh[j & 3], 0, 0, 0);
      float p0 = 0.f;
#pragma unroll
      for (int reg = 0; reg < 4; reg++)
        p0 = fmaf(Treg[reg], (hh[0][reg] + hh[1][reg]) + (hh[2][reg] + hh[3][reg]), p0);
      part[0] = p0;
    }
  } else {
    // tile: 32 consecutive floats x 512 rows at stride 2048 floats
    const float4* src4 = ((const float4*)vb) + ((size_t)b << 18) + chunk * 8;
#pragma unroll
    for (int j = 0; j < 8; j++) {
      int B = j * 256 + t;
      int row = B >> 2;
      int c4 = (B & 3) * 2;
      float4 aa = src4[row * 512 + c4], cc = src4[row * 512 + c4 + 1];
      half8 hh;
      hh[0] = (_Float16)aa.x; hh[1] = (_Float16)aa.y; hh[2] = (_Float16)aa.z; hh[3] = (_Float16)aa.w;
      hh[4] = (_Float16)cc.x; hh[5] = (_Float16)cc.y; hh[6] = (_Float16)cc.z; hh[7] = (_Float16)cc.w;
      HB[swzB(B)] = hh;
    }
  }
  __syncthreads();

  if (mode == 0) {
    // image0 LDS windows: p = P, q = 16 - p  -> win 1..7 <-> q 12..6
    part[1] += windowM<4>(HB, Treg);
    part[2] += windowM<5>(HB, Treg);
    part[3] += windowM<6>(HB, Treg);
    part[4] += windowM<7>(HB, Treg);
    part[5] += windowM<8>(HB, Treg);
    part[6] += windowM<9>(HB, Treg);
    part[7] += windowM<10>(HB, Treg);
    // re-read staged blocks, in-place transpose -> image1 (rot+3)
    half8 h2[8];
#pragma unroll
    for (int j = 0; j < 8; j++) h2[j] = HB[swzB(j * 256 + t)];
    __syncthreads();  // all image0 reads complete before overwrite
#pragma unroll
    for (int e = 0; e < 8; e++) {
      half8 v;
#pragma unroll
      for (int j = 0; j < 8; j++) v[j] = h2[j][e];
      HB[swzB(8 * t + e)] = v;
    }
    __syncthreads();
    // image1: p = P - 3 in {0,1,2} -> win 8,9,10 <-> q 16,15,14
    part[8]  += windowM<3>(HB, Treg);
    part[9]  += windowM<4>(HB, Treg);
    part[10] += windowM<5>(HB, Treg);
  } else {
    // p = P + 6 in {11..16} -> win 0..5 <-> q 5..0
    part[0] += windowM<5>(HB, Treg);
    part[1] += windowM<6>(HB, Treg);
    part[2] += windowM<7>(HB, Treg);
    part[3] += windowM<8>(HB, Treg);
    part[4] += windowM<9>(HB, Treg);
    part[5] += windowM<10>(HB, Treg);
  }
  __syncthreads();  // all reads of HB done; safe to alias reduce scratch

  float* red2 = (float*)HB;  // 12*256 floats = 12 KB
#pragma unroll
  for (int k = 0; k < 11; k++) red2[k * 256 + t] = part[k];
  red2[11 * 256 + t] = nsum;
  __syncthreads();

  // batched cross-block reduction: 16-thread group per value (12 live groups)
  const int win = t >> 4, idx16 = t & 15;
  const float4* r4 = (const float4*)red2;
  float4 q0 = r4[win * 64 + idx16],      q1 = r4[win * 64 + 16 + idx16];
  float4 q2 = r4[win * 64 + 32 + idx16], q3 = r4[win * 64 + 48 + idx16];
  float s1 = ((q0.x + q0.y) + (q0.z + q0.w)) + ((q1.x + q1.y) + (q1.z + q1.w)) +
             ((q2.x + q2.y) + (q2.z + q2.w)) + ((q3.x + q3.y) + (q3.z + q3.w));
#pragma unroll
  for (int off = 8; off; off >>= 1) s1 += __shfl_down(s1, off, 16);

  if (idx16 == 0) {
    if (mode == 0) {
      if (win < 11) {
        int q = (win < 8) ? (13 - win) : (24 - win);
        if (use_part) ws[WS_PART + (b * 17 + q) * 64 + chunk] = s1;
        else          atomicAdd(ws + WS_S + b * 17 + q, s1);
      } else if (win == 11) {
        if (use_part) ws[WS_NPART + b * 64 + chunk] = s1;
        else          atomicAdd(ws + WS_N + b, s1);
      }
    } else {
      if (win < 6) {
        int q = 5 - win;
        if (use_part) ws[WS_PART + (b * 17 + q) * 64 + chunk] = s1;
        else          atomicAdd(ws + WS_S + b * 17 + q, s1);
      }
    }
  }
}

__global__ void finalize_kernel(const float* __restrict__ ws, float* __restrict__ out,
                                int use_part) {
  int i = blockIdx.x * 256 + threadIdx.x;
  if (i < 544) {
    int b = i / 17;
    float s, n;
    if (use_part) {
      const float* sp = ws + WS_PART + i * 64;
      s = 0.f;
#pragma unroll 8
      for (int c = 0; c < 64; c++) s += sp[c];
      const float* np = ws + WS_NPART + b * 64;
      n = 0.f;
#pragma unroll 8
      for (int c = 0; c < 64; c++) n += np[c];
    } else {
      s = ws[WS_S + i];
      n = ws[WS_N + b];
    }
    out[i] = s / fmaxf(n, 1e-24f);
  }
}

extern "C" void kernel_launch(void* const* d_in, const int* in_sizes, int n_in,
                              void* d_out, int out_size, void* d_ws, size_t ws_size,
                              hipStream_t stream) {
  const float* vb  = (const float*)d_in[0];
  const float* wgt = (const float*)d_in[1];
  float* out = (float*)d_out;
  float* ws  = (float*)d_ws;
  int use_part = (ws_size >= (size_t)WS_NEED_BYTES) ? 1 : 0;

  build_T_kernel<<<1, 256, 0, stream>>>(wgt, ws);
  passAll_kernel<<<4096, 256, 0, stream>>>(vb, ws, use_part);
  finalize_kernel<<<3, 256, 0, stream>>>(ws, out, use_part);
}